// Round 15
// baseline (338.475 us; speedup 1.0000x reference)
//
#include <hip/hip_runtime.h>
#include <hip/hip_bf16.h>
#include <math.h>

#define BB 8
#define TT 1024
#define DD 256
#define HH 8
#define BT 8192   // B*T

typedef __attribute__((ext_vector_type(4))) float f32x4;
typedef __attribute__((ext_vector_type(16))) float f32x16;
typedef __attribute__((ext_vector_type(8))) short short8;
typedef __attribute__((ext_vector_type(4))) short short4v;
typedef __attribute__((ext_vector_type(8))) __bf16 bf16x8;

__device__ inline float bf2f(short s) {
  unsigned int u = ((unsigned int)(unsigned short)s) << 16;
  return __builtin_bit_cast(float, u);
}
__device__ inline short f2bf(float f) {
  unsigned int u = __builtin_bit_cast(unsigned int, f);
  unsigned int lsb = (u >> 16) & 1u;
  u += 0x7fffu + lsb;
  return (short)(u >> 16);
}
__device__ inline unsigned int cvtpk(float lo, float hi) {
  unsigned int r;
  asm("v_cvt_pk_bf16_f32 %0, %1, %2" : "=v"(r) : "v"(lo), "v"(hi));
  return r;
}

__device__ inline f32x4 mfma16(short8 a, short8 b, f32x4 c) {
  return __builtin_amdgcn_mfma_f32_16x16x32_bf16(
      __builtin_bit_cast(bf16x8, a), __builtin_bit_cast(bf16x8, b), c, 0, 0, 0);
}
__device__ inline f32x16 mfma32(short8 a, short8 b, f32x16 c) {
  return __builtin_amdgcn_mfma_f32_32x32x16_bf16(
      __builtin_bit_cast(bf16x8, a), __builtin_bit_cast(bf16x8, b), c, 0, 0, 0);
}

__device__ inline void gload_lds16(void* lds, const void* g) {
  __builtin_amdgcn_global_load_lds(
      (const __attribute__((address_space(1))) unsigned int*)g,
      (__attribute__((address_space(3))) unsigned int*)lds, 16, 0, 0);
}

// ---------------- all weights fp32 -> bf16, one kernel ----------------
__global__ __launch_bounds__(256) void cvt_all(
    const float4* __restrict__ s0, short4v* __restrict__ d0, int n0,
    const float4* __restrict__ s1, short4v* __restrict__ d1, int n1,
    const float4* __restrict__ s2, short4v* __restrict__ d2, int n2,
    const float4* __restrict__ s3, short4v* __restrict__ d3, int n3)
{
  int i = blockIdx.x * 256 + threadIdx.x;
  const float4* s; short4v* d;
  if (i < n0) { s = s0 + i; d = d0 + i; }
  else if ((i -= n0) < n1) { s = s1 + i; d = d1 + i; }
  else if ((i -= n1) < n2) { s = s2 + i; d = d2 + i; }
  else if ((i -= n2) < n3) { s = s3 + i; d = d3 + i; }
  else return;
  float4 v = *s;
  short4v o;
  o[0] = f2bf(v.x); o[1] = f2bf(v.y); o[2] = f2bf(v.z); o[3] = f2bf(v.w);
  *d = o;
}

// ---------------- LayerNorm (double LN) — layer-0 entry only ----------------
__global__ __launch_bounds__(256) void ln_kernel(
    const float* __restrict__ Xin,
    const float* __restrict__ g1, const float* __restrict__ b1,
    const float* __restrict__ g2, const float* __restrict__ b2,
    short* __restrict__ out)
{
  const int row = blockIdx.x * 4 + (threadIdx.x >> 6);
  const int lane = threadIdx.x & 63;
  const float4 v = *(const float4*)(Xin + (size_t)row * 256 + lane * 4);
  float y[4] = {v.x, v.y, v.z, v.w};

  float s = y[0] + y[1] + y[2] + y[3];
  #pragma unroll
  for (int m = 32; m >= 1; m >>= 1) s += __shfl_xor(s, m, 64);
  float mean = s * (1.0f / 256.0f);
  float sq = 0.f;
  #pragma unroll
  for (int i = 0; i < 4; ++i) { y[i] -= mean; sq += y[i] * y[i]; }
  #pragma unroll
  for (int m = 32; m >= 1; m >>= 1) sq += __shfl_xor(sq, m, 64);
  float rs = rsqrtf(sq * (1.0f / 256.0f) + 1e-6f);
  #pragma unroll
  for (int i = 0; i < 4; ++i) y[i] = y[i] * rs * g1[lane * 4 + i] + b1[lane * 4 + i];

  float s2 = y[0] + y[1] + y[2] + y[3];
  #pragma unroll
  for (int m = 32; m >= 1; m >>= 1) s2 += __shfl_xor(s2, m, 64);
  float m2 = s2 * (1.0f / 256.0f);
  float sq2 = 0.f;
  #pragma unroll
  for (int i = 0; i < 4; ++i) { y[i] -= m2; sq2 += y[i] * y[i]; }
  #pragma unroll
  for (int m = 32; m >= 1; m >>= 1) sq2 += __shfl_xor(sq2, m, 64);
  float rs2 = rsqrtf(sq2 * (1.0f / 256.0f) + 1e-6f);
  #pragma unroll
  for (int i = 0; i < 4; ++i) y[i] = y[i] * rs2 * g2[lane * 4 + i] + b2[lane * 4 + i];

  #pragma unroll
  for (int i = 0; i < 4; ++i) out[(size_t)row * 256 + lane * 4 + i] = f2bf(y[i]);
}

// ------- GEMM: C[M,N] = A[M,K] @ Bw[N,K]^T, BK=64, 2-phase dbuf staging -------
// EPI 2: Out_bf = bf16(gelu_tanh(acc + bias))                            (FFN1)
// EPI 4: packed qkv: Qp/Kp[(bh)*1024+t][32] (l2normed, Q*C2), vT[bh][d][t] (QKV)
template<int BN, int EPI>
__global__ __launch_bounds__(256) void gemm_bt(
    const short* __restrict__ A, const short* __restrict__ Bw,
    const float* __restrict__ bias,
    short* __restrict__ O0, short* __restrict__ O1, short* __restrict__ O2,
    int M, int N, int K)
{
  constexpr int MI = (BN == 128) ? 4 : 2;
  __shared__ __align__(16) short A_s[2][128 * 64];
  __shared__ __align__(16) short B_s[2][BN * 64];
  const int tid = threadIdx.x;
  const int lane = tid & 63;
  const int w = tid >> 6;
  const int lo4 = lane & 15, hi2 = lane >> 4;
  int wm, wn0;
  if (BN == 128) { wm = (w >> 1) * 64; wn0 = (w & 1) * 64; }
  else           { wm = w * 32;        wn0 = 0; }
  const int bid = blockIdx.x + blockIdx.y * gridDim.x;
  const int nwg = gridDim.x * gridDim.y;
  const int wg = (bid & 7) * (nwg >> 3) + (bid >> 3);
  const int tM = (wg / gridDim.x) * 128, tN = (wg % gridDim.x) * BN;

  f32x4 acc[MI][4];
  #pragma unroll
  for (int i = 0; i < MI; ++i)
    #pragma unroll
    for (int j = 0; j < 4; ++j) acc[i][j] = (f32x4){0.f, 0.f, 0.f, 0.f};

  auto stage = [&](int buf, int k0) {
    #pragma unroll
    for (int ri = 0; ri < 4; ++ri) {
      int o = ri * 2048 + tid * 8;
      int row = o >> 6;
      int col = (o & 63) ^ ((row & 7) << 3);
      gload_lds16(&A_s[buf][ri * 2048 + w * 512], A + (size_t)(tM + row) * K + k0 + col);
    }
    #pragma unroll
    for (int ri = 0; ri < BN / 32; ++ri) {
      int o = ri * 2048 + tid * 8;
      int row = o >> 6;
      int col = (o & 63) ^ ((row & 7) << 3);
      gload_lds16(&B_s[buf][ri * 2048 + w * 512], Bw + (size_t)(tN + row) * K + k0 + col);
    }
  };

  const int nt = K >> 6;
  stage(0, 0);
  __syncthreads();
  for (int t = 0; t < nt; ++t) {
    const int cur = t & 1;
    if (t + 1 < nt) stage(cur ^ 1, (t + 1) << 6);
    #pragma unroll
    for (int kc = 0; kc < 2; ++kc) {
      short8 af[MI], bfr[4];
      #pragma unroll
      for (int i = 0; i < MI; ++i) {
        int row = wm + i * 16 + lo4;
        af[i] = *(const short8*)&A_s[cur][row * 64 + ((kc * 32 + hi2 * 8) ^ ((row & 7) << 3))];
      }
      #pragma unroll
      for (int j = 0; j < 4; ++j) {
        int row = wn0 + j * 16 + lo4;
        bfr[j] = *(const short8*)&B_s[cur][row * 64 + ((kc * 32 + hi2 * 8) ^ ((row & 7) << 3))];
      }
      #pragma unroll
      for (int i = 0; i < MI; ++i)
        #pragma unroll
        for (int j = 0; j < 4; ++j)
          acc[i][j] = mfma16(af[i], bfr[j], acc[i][j]);
    }
    __syncthreads();
  }

  if (EPI == 4) {
    #pragma unroll
    for (int i = 0; i < MI; ++i)
      #pragma unroll
      for (int j = 0; j < 4; ++j)
        #pragma unroll
        for (int r = 0; r < 4; ++r)
          acc[i][j][r] += bias[tN + wn0 + j * 16 + lo4];
    if (tN >= 512) {
      // V: direct transposed write vT[bh][d][t], short4 over r (4 consecutive t)
      #pragma unroll
      for (int i = 0; i < MI; ++i) {
        #pragma unroll
        for (int j = 0; j < 4; ++j) {
          short4v o;
          #pragma unroll
          for (int r = 0; r < 4; ++r) o[r] = f2bf(acc[i][j][r]);
          int row0 = tM + wm + i * 16 + hi2 * 4;
          int colr = (tN + wn0 + j * 16 + lo4) - 512;
          int h = colr >> 5, d = colr & 31;
          int b = row0 >> 10, t0 = row0 & 1023;
          *(short4v*)(O2 + (((size_t)(b * 8 + h) * 32 + d) << 10) + t0) = o;
        }
      }
      return;
    }
    {  // Q or K: per-head l2norm (j-pairs {0,1},{2,3})
      const float C2 = 0.25503489702966368f;   // (1/sqrt(32)) * log2(e)
      const float sc = (tN < 256) ? C2 : 1.0f;
      #pragma unroll
      for (int i = 0; i < MI; ++i) {
        #pragma unroll
        for (int r = 0; r < 4; ++r) {
          float s01 = acc[i][0][r] * acc[i][0][r] + acc[i][1][r] * acc[i][1][r];
          float s23 = acc[i][2][r] * acc[i][2][r] + acc[i][3][r] * acc[i][3][r];
          #pragma unroll
          for (int m = 1; m <= 8; m <<= 1) {
            s01 += __shfl_xor(s01, m, 64);
            s23 += __shfl_xor(s23, m, 64);
          }
          float n01 = sc / fmaxf(sqrtf(s01), 1e-8f);
          float n23 = sc / fmaxf(sqrtf(s23), 1e-8f);
          acc[i][0][r] *= n01; acc[i][1][r] *= n01;
          acc[i][2][r] *= n23; acc[i][3][r] *= n23;
        }
      }
    }
    short* dst = (tN < 256) ? O0 : O1;
    #pragma unroll
    for (int i = 0; i < MI; ++i)
      #pragma unroll
      for (int j = 0; j < 4; ++j)
        #pragma unroll
        for (int r = 0; r < 4; ++r) {
          int row = tM + wm + i * 16 + hi2 * 4 + r;
          int colr = (tN + wn0 + j * 16 + lo4) & 255;
          int h = colr >> 5, d = colr & 31;
          size_t idx = (((size_t)((row >> 10) * 8 + h) << 10) | (size_t)(row & 1023)) * 32 + d;
          dst[idx] = f2bf(acc[i][j][r]);
        }
    return;
  }

  #pragma unroll
  for (int i = 0; i < MI; ++i) {
    #pragma unroll
    for (int j = 0; j < 4; ++j) {
      #pragma unroll
      for (int r = 0; r < 4; ++r) {
        int row = tM + wm + i * 16 + hi2 * 4 + r;
        int col = tN + wn0 + j * 16 + lo4;
        float v = acc[i][j][r] + bias[col];
        size_t idx = (size_t)row * N + col;
        if (EPI == 2) {
          // gelu tanh-form: v * t/(t+1), t = exp2(2*y*log2e)
          float t1 = v * v;
          float arg = fminf(v * (1.0f + 0.044715f * t1) * 2.3022077f, 80.0f);
          float ex;
          asm("v_exp_f32 %0, %1" : "=v"(ex) : "v"(arg));
          float gl = v * ex * __builtin_amdgcn_rcpf(ex + 1.0f);
          O0[idx] = f2bf(gl);
        } else {
          O0[idx] = f2bf(v);
        }
      }
    }
  }
}

// ---- gemm_ln: BM=32 full-row; 512 threads / 8 waves (wave = 32-col span) ----
// Residual X carried as bf16 (Xb). MODE 0 (Wo): Xb = (firstL? Xf : Xb) + ts*0.5*v;
// h = LN(X). MODE 1 (FFN2): Xb = clip(Xb + ts*v, ±100) [+ fp32 out at last layer];
// h = LN(LN(X)) if doLN.
template<int MODE>
__global__ __launch_bounds__(512) void gemm_ln(
    const short* __restrict__ A, const short* __restrict__ Bw,
    const float* __restrict__ bias,
    const float* __restrict__ Xf_in, short* __restrict__ Xb, float* __restrict__ Xf_out,
    short* __restrict__ Obf, const float* __restrict__ scale_p,
    const float* __restrict__ gA, const float* __restrict__ bA,
    const float* __restrict__ gB, const float* __restrict__ bB,
    int K, int doLN, int firstL, int lastL)
{
  __shared__ __align__(16) short A_s[2][32 * 64];
  __shared__ __align__(16) short B_s[2][256 * 64];
  __shared__ float Red[2][32][8][2];
  const int tid = threadIdx.x;
  const int lane = tid & 63;
  const int w = tid >> 6;                // 0..7
  const int lo4 = lane & 15, hi2 = lane >> 4;
  const int tM = blockIdx.x * 32;
  const int wn0 = w * 32;                // wave's 32-col span

  f32x4 acc[2][2];
  #pragma unroll
  for (int i = 0; i < 2; ++i)
    #pragma unroll
    for (int j = 0; j < 2; ++j) acc[i][j] = (f32x4){0.f, 0.f, 0.f, 0.f};

  auto stage = [&](int buf, int k0) {
    if (tid < 256) {
      int o = tid * 8;
      int row = o >> 6;
      int col = (o & 63) ^ ((row & 7) << 3);
      gload_lds16(&A_s[buf][w * 512], A + (size_t)(tM + row) * K + k0 + col);
    }
    #pragma unroll
    for (int ri = 0; ri < 4; ++ri) {
      int o = ri * 4096 + tid * 8;
      int row = o >> 6;
      int col = (o & 63) ^ ((row & 7) << 3);
      gload_lds16(&B_s[buf][ri * 4096 + w * 512], Bw + (size_t)row * K + k0 + col);
    }
  };

  const int nt = K >> 6;
  stage(0, 0);
  __syncthreads();
  for (int t = 0; t < nt; ++t) {
    const int cur = t & 1;
    if (t + 1 < nt) stage(cur ^ 1, (t + 1) << 6);
    #pragma unroll
    for (int kc = 0; kc < 2; ++kc) {
      short8 af[2], bfr[2];
      #pragma unroll
      for (int i = 0; i < 2; ++i) {
        int row = i * 16 + lo4;
        af[i] = *(const short8*)&A_s[cur][row * 64 + ((kc * 32 + hi2 * 8) ^ ((row & 7) << 3))];
      }
      #pragma unroll
      for (int j = 0; j < 2; ++j) {
        int row = wn0 + j * 16 + lo4;
        bfr[j] = *(const short8*)&B_s[cur][row * 64 + ((kc * 32 + hi2 * 8) ^ ((row & 7) << 3))];
      }
      #pragma unroll
      for (int i = 0; i < 2; ++i)
        #pragma unroll
        for (int j = 0; j < 2; ++j)
          acc[i][j] = mfma16(af[i], bfr[j], acc[i][j]);
    }
    __syncthreads();
  }

  const float ts = tanhf(scale_p[0]);
  float xv[2][2][4];
  #pragma unroll
  for (int i = 0; i < 2; ++i)
    #pragma unroll
    for (int j = 0; j < 2; ++j)
      #pragma unroll
      for (int r = 0; r < 4; ++r) {
        int row = i * 16 + hi2 * 4 + r;
        int col = wn0 + j * 16 + lo4;
        float v = acc[i][j][r] + bias[col];
        size_t idx = (size_t)(tM + row) * 256 + col;
        float xn;
        if (MODE == 0) {
          float xo = firstL ? Xf_in[idx] : bf2f(Xb[idx]);
          xn = xo + ts * 0.5f * v;
        } else {
          xn = bf2f(Xb[idx]) + ts * v;
          xn = fminf(100.f, fmaxf(-100.f, xn));
          if (lastL) Xf_out[idx] = xn;
        }
        Xb[idx] = f2bf(xn);
        xv[i][j][r] = xn;
      }

  if (!doLN) return;

  #pragma unroll
  for (int i = 0; i < 2; ++i)
    #pragma unroll
    for (int r = 0; r < 4; ++r) {
      float s = xv[i][0][r] + xv[i][1][r];
      float q = xv[i][0][r] * xv[i][0][r] + xv[i][1][r] * xv[i][1][r];
      #pragma unroll
      for (int m = 1; m <= 8; m <<= 1) { s += __shfl_xor(s, m, 64); q += __shfl_xor(q, m, 64); }
      if (lo4 == 0) { Red[0][i * 16 + hi2 * 4 + r][w][0] = s; Red[0][i * 16 + hi2 * 4 + r][w][1] = q; }
    }
  __syncthreads();
  #pragma unroll
  for (int i = 0; i < 2; ++i)
    #pragma unroll
    for (int r = 0; r < 4; ++r) {
      int row = i * 16 + hi2 * 4 + r;
      float s = 0.f, q = 0.f;
      #pragma unroll
      for (int ww = 0; ww < 8; ++ww) { s += Red[0][row][ww][0]; q += Red[0][row][ww][1]; }
      float mu = s * (1.0f / 256.0f);
      float var = q * (1.0f / 256.0f) - mu * mu;
      float rs = rsqrtf(var + 1e-6f);
      #pragma unroll
      for (int j = 0; j < 2; ++j) {
        int col = wn0 + j * 16 + lo4;
        xv[i][j][r] = (xv[i][j][r] - mu) * rs * gA[col] + bA[col];
      }
    }

  if (MODE == 1) {
    __syncthreads();
    #pragma unroll
    for (int i = 0; i < 2; ++i)
      #pragma unroll
      for (int r = 0; r < 4; ++r) {
        float s = xv[i][0][r] + xv[i][1][r];
        float q = xv[i][0][r] * xv[i][0][r] + xv[i][1][r] * xv[i][1][r];
        #pragma unroll
        for (int m = 1; m <= 8; m <<= 1) { s += __shfl_xor(s, m, 64); q += __shfl_xor(q, m, 64); }
        if (lo4 == 0) { Red[1][i * 16 + hi2 * 4 + r][w][0] = s; Red[1][i * 16 + hi2 * 4 + r][w][1] = q; }
      }
    __syncthreads();
    #pragma unroll
    for (int i = 0; i < 2; ++i)
      #pragma unroll
      for (int r = 0; r < 4; ++r) {
        int row = i * 16 + hi2 * 4 + r;
        float s = 0.f, q = 0.f;
        #pragma unroll
        for (int ww = 0; ww < 8; ++ww) { s += Red[1][row][ww][0]; q += Red[1][row][ww][1]; }
        float mu = s * (1.0f / 256.0f);
        float var = q * (1.0f / 256.0f) - mu * mu;
        float rs = rsqrtf(var + 1e-6f);
        #pragma unroll
        for (int j = 0; j < 2; ++j) {
          int col = wn0 + j * 16 + lo4;
          xv[i][j][r] = (xv[i][j][r] - mu) * rs * gB[col] + bB[col];
        }
      }
  }

  #pragma unroll
  for (int i = 0; i < 2; ++i)
    #pragma unroll
    for (int j = 0; j < 2; ++j)
      #pragma unroll
      for (int r = 0; r < 4; ++r) {
        int row = i * 16 + hi2 * 4 + r;
        int col = wn0 + j * 16 + lo4;
        Obf[(size_t)(tM + row) * 256 + col] = f2bf(xv[i][j][r]);
      }
}

// ------- fused causal attention: packed Qp/Kp/vT, 2-way KV split per q-tile -----
__device__ __forceinline__ void pv_acc(const unsigned int* PKO, int half_,
                                       short8 vb, int hi1, f32x16& acc) {
  unsigned int keep0 = hi1 ? PKO[4 * half_ + 2] : PKO[4 * half_ + 0];
  unsigned int keep1 = hi1 ? PKO[4 * half_ + 3] : PKO[4 * half_ + 1];
  unsigned int send0 = hi1 ? PKO[4 * half_ + 0] : PKO[4 * half_ + 2];
  unsigned int send1 = hi1 ? PKO[4 * half_ + 1] : PKO[4 * half_ + 3];
  unsigned int r0 = (unsigned int)__shfl_xor((int)send0, 32, 64);
  unsigned int r1 = (unsigned int)__shfl_xor((int)send1, 32, 64);
  union { unsigned int u[4]; short8 s; } fa;
  fa.u[0] = hi1 ? r0 : keep0;
  fa.u[1] = hi1 ? r1 : keep1;
  fa.u[2] = hi1 ? keep0 : r0;
  fa.u[3] = hi1 ? keep1 : r1;
  acc = mfma32(fa.s, vb, acc);
}

template<bool KG1, bool M0, bool M1>
__device__ __forceinline__ void attn_tile(
    int t, const short* __restrict__ Kbase, const short* __restrict__ VTl,
    const short8* qb, unsigned int pm0, unsigned int pm1, int lo5, int hi1,
    f32x16& oaccA, f32x16& oaccB, float& rsum)
{
  const short* kp0 = Kbase + (size_t)(t * 64 + lo5) * 32;
  short8 k00 = *(const short8*)(kp0 + hi1 * 8);
  short8 k01 = *(const short8*)(kp0 + 16 + hi1 * 8);
  short8 k10, k11;
  if (KG1) {
    const short* kp1 = Kbase + (size_t)(t * 64 + 32 + lo5) * 32;
    k10 = *(const short8*)(kp1 + hi1 * 8);
    k11 = *(const short8*)(kp1 + 16 + hi1 * 8);
  }
  const short* vp = VTl + t * 64 + hi1 * 8;
  short8 vb0 = *(const short8*)(vp);
  short8 vb1 = *(const short8*)(vp + 16);
  short8 vb2, vb3;
  if (KG1) {
    vb2 = *(const short8*)(vp + 32);
    vb3 = *(const short8*)(vp + 48);
  }
  unsigned int pk0[8], pk1[8];
  {
    f32x16 z = (f32x16)0.0f;
    z = mfma32(k00, qb[0], z);
    z = mfma32(k01, qb[1], z);
    float pr[16];
    #pragma unroll
    for (int r = 0; r < 16; ++r) {
      float sv = __builtin_amdgcn_fmed3f(z[r], -14.4269504f, 14.4269504f);
      float pe;
      asm("v_exp_f32 %0, %1" : "=v"(pe) : "v"(sv));
      const int keyrel = (r & 3) + 8 * (r >> 2) + 4 * hi1;
      if (M0) pe = (keyrel > lo5) ? 0.f : pe;
      if (pm0) pe = ((pm0 >> keyrel) & 1u) ? 0.f : pe;
      pr[r] = pe;
      rsum += pe;
    }
    #pragma unroll
    for (int i = 0; i < 8; ++i) pk0[i] = cvtpk(pr[2 * i], pr[2 * i + 1]);
  }
  if (KG1) {
    f32x16 z = (f32x16)0.0f;
    z = mfma32(k10, qb[0], z);
    z = mfma32(k11, qb[1], z);
    float pr[16];
    #pragma unroll
    for (int r = 0; r < 16; ++r) {
      float sv = __builtin_amdgcn_fmed3f(z[r], -14.4269504f, 14.4269504f);
      float pe;
      asm("v_exp_f32 %0, %1" : "=v"(pe) : "v"(sv));
      const int keyrel = (r & 3) + 8 * (r >> 2) + 4 * hi1;
      if (M1) pe = (keyrel > lo5) ? 0.f : pe;
      if (pm1) pe = ((pm1 >> keyrel) & 1u) ? 0.f : pe;
      pr[r] = pe;
      rsum += pe;
    }
    #pragma unroll
    for (int i = 0; i < 8; ++i) pk1[i] = cvtpk(pr[2 * i], pr[2 * i + 1]);
  }
  pv_acc(pk0, 0, vb0, hi1, oaccA);
  pv_acc(pk0, 1, vb1, hi1, oaccB);
  if (KG1) {
    pv_acc(pk1, 0, vb2, hi1, oaccA);
    pv_acc(pk1, 1, vb3, hi1, oaccB);
  }
}

__global__ __launch_bounds__(256, 2) void attn_kernel(
    const short* __restrict__ Qp, const short* __restrict__ Kp,
    const short* __restrict__ vT, const unsigned char* __restrict__ pad,
    short* __restrict__ ao)
{
  __shared__ float Red[2][17][64];
  const int tid = threadIdx.x, lane = tid & 63, w = tid >> 6;
  const int lo5 = lane & 31, hi1 = lane >> 5;
  const int bid = blockIdx.x;            // 1024
  const int b = bid & 7;                 // XCD-local batch
  const int h = (bid >> 3) & 7;
  const int bj = bid >> 6;               // 0..15
  const int p = w >> 1;                  // pair id
  const int half = w & 1;                // t-parity this wave owns
  const int j = p ? (31 - bj) : bj;      // q-tile 0..31
  const size_t rowbase = (size_t)b * TT;
  const int bh = b * 8 + h;
  const int qrow = j * 32 + lo5;
  const int ntile = (j >> 1) + 1;

  const short* Kbase = Kp + ((size_t)bh << 10) * 32;
  const short* VTl = vT + ((size_t)bh * 32 + lo5) * 1024;

  const ulonglong2 pv = *(const ulonglong2*)(pad + rowbase + lane * 16);
  const unsigned long long anyp = __ballot((pv.x | pv.y) != 0ull);

  short8 qb[2];
  #pragma unroll
  for (int c2 = 0; c2 < 2; ++c2)
    qb[c2] = *(const short8*)(Qp + (((size_t)bh << 10) + qrow) * 32 + c2 * 16 + hi1 * 8);

  f32x16 oaccA = (f32x16)0.0f;
  f32x16 oaccB = (f32x16)0.0f;
  float rsum = 0.f;

  for (int t = half; t < ntile; t += 2) {
    unsigned long long pm = 0;
    if ((anyp >> (4 * t)) & 0xFull)
      pm = __ballot(pad[rowbase + t * 64 + lane] != 0);
    unsigned int pm0 = (unsigned int)pm, pm1 = (unsigned int)(pm >> 32);
    if (t + 1 < ntile)
      attn_tile<true, false, false>(t, Kbase, VTl, qb, pm0, pm1, lo5, hi1, oaccA, oaccB, rsum);
    else if (j & 1)
      attn_tile<true, false, true>(t, Kbase, VTl, qb, pm0, pm1, lo5, hi1, oaccA, oaccB, rsum);
    else
      attn_tile<false, true, false>(t, Kbase, VTl, qb, pm0, pm1, lo5, hi1, oaccA, oaccB, rsum);
  }

  if (half) {
    #pragma unroll
    for (int r = 0; r < 16; ++r) Red[p][r][lane] = oaccA[r] + oaccB[r];
    Red[p][16][lane] = rsum;
  }
  __syncthreads();
  if (!half) {
    #pragma unroll
    for (int r = 0; r < 16; ++r) oaccA[r] += oaccB[r] + Red[p][r][lane];
    rsum += Red[p][16][lane];
    rsum += __shfl_xor(rsum, 32, 64);
    float rinv = 1.0f / fmaxf(rsum, 1e-30f);
    #pragma unroll
    for (int r = 0; r < 16; ++r) {
      int ql = (r & 3) + 8 * (r >> 2) + 4 * hi1;
      float riv = __shfl(rinv, ql, 64);
      int qg = j * 32 + ql;
      ao[(rowbase + qg) * 256 + h * 32 + lo5] = f2bf(oaccA[r] * riv);
    }
  }
}

extern "C" void kernel_launch(void* const* d_in, const int* in_sizes, int n_in,
                              void* d_out, int out_size, void* d_ws, size_t ws_size,
                              hipStream_t stream) {
  const float* x_in  = (const float*)d_in[0];
  const unsigned char* pad = (const unsigned char*)d_in[1];
  const float* ln1_g = (const float*)d_in[2];
  const float* ln1_b = (const float*)d_in[3];
  const float* qn_g  = (const float*)d_in[4];
  const float* qn_b  = (const float*)d_in[5];
  const float* Wqkv  = (const float*)d_in[6];
  const float* bqkv  = (const float*)d_in[7];
  const float* Wo    = (const float*)d_in[8];
  const float* bo    = (const float*)d_in[9];
  const float* ln2_g = (const float*)d_in[10];
  const float* ln2_b = (const float*)d_in[11];
  const float* W1    = (const float*)d_in[12];
  const float* b1    = (const float*)d_in[13];
  const float* W2    = (const float*)d_in[14];
  const float* b2    = (const float*)d_in[15];
  const float* alpha = (const float*)d_in[16];
  const float* beta  = (const float*)d_in[17];

  char* ws = (char*)d_ws;
  size_t off = 0;
  short* wqkv_bf = (short*)(ws + off); off += (size_t)4 * 768 * 256 * 2;
  short* wo_bf   = (short*)(ws + off); off += (size_t)4 * 256 * 256 * 2;
  short* w1_bf   = (short*)(ws + off); off += (size_t)4 * 1024 * 256 * 2;
  short* w2_bf   = (short*)(ws + off); off += (size_t)4 * 256 * 1024 * 2;
  short* h_bf    = (short*)(ws + off); off += (size_t)BT * 256 * 2;
  short* Qp_bf   = (short*)(ws + off); off += (size_t)BT * 256 * 2;
  short* Kp_bf   = (short*)(ws + off); off += (size_t)BT * 256 * 2;
  short* vT_bf   = (short*)(ws + off); off += (size_t)BT * 256 * 2;
  short* ao_bf   = (short*)(ws + off); off += (size_t)BT * 256 * 2;
  short* Xb_bf   = (short*)(ws + off); off += (size_t)BT * 256 * 2;
  short* g_bf    = (short*)(ws + off); off += (size_t)BT * 1024 * 2;

  float* X = (float*)d_out;

  cvt_all<<<3072, 256, 0, stream>>>(
      (const float4*)Wqkv, (short4v*)wqkv_bf, 4 * 768 * 256 / 4,
      (const float4*)Wo,   (short4v*)wo_bf,   4 * 256 * 256 / 4,
      (const float4*)W1,   (short4v*)w1_bf,   4 * 1024 * 256 / 4,
      (const float4*)W2,   (short4v*)w2_bf,   4 * 256 * 1024 / 4);

  // layer-0 entry LN (double) reads x_in directly
  ln_kernel<<<2048, 256, 0, stream>>>(x_in, ln1_g, ln1_b, qn_g, qn_b, h_bf);

  for (int l = 0; l < 4; ++l) {
    gemm_bt<64, 4><<<dim3(12, 64), 256, 0, stream>>>(h_bf, wqkv_bf + (size_t)l * 768 * 256,
                                                     bqkv + l * 768, Qp_bf, Kp_bf, vT_bf,
                                                     8192, 768, 256);
    attn_kernel<<<1024, 256, 0, stream>>>(Qp_bf, Kp_bf, vT_bf, pad, ao_bf);
    gemm_ln<0><<<256, 512, 0, stream>>>(ao_bf, wo_bf + (size_t)l * 256 * 256,
                                        bo + l * 256, x_in, Xb_bf, nullptr,
                                        h_bf, alpha + l,
                                        ln2_g + l * 256, ln2_b + l * 256,
                                        nullptr, nullptr, 256, 1, (l == 0) ? 1 : 0, 0);
    gemm_bt<128, 2><<<dim3(8, 64), 256, 0, stream>>>(h_bf, w1_bf + (size_t)l * 1024 * 256,
                                                     b1 + l * 1024, g_bf, nullptr, nullptr,
                                                     8192, 1024, 256);
    const int nl = (l < 3) ? (l + 1) : 0;  // dummy params when doLN=0
    gemm_ln<1><<<256, 512, 0, stream>>>(g_bf, w2_bf + (size_t)l * 256 * 1024,
                                        b2 + l * 256, nullptr, Xb_bf, X,
                                        h_bf, beta + l,
                                        ln1_g + nl * 256, ln1_b + nl * 256,
                                        qn_g + nl * 256, qn_b + nl * 256,
                                        1024, (l < 3) ? 1 : 0, 0, (l == 3) ? 1 : 0);
  }
}

// Round 16
// 326.878 us; speedup vs baseline: 1.0355x; 1.0355x over previous
//
#include <hip/hip_runtime.h>
#include <hip/hip_bf16.h>
#include <math.h>

#define BB 8
#define TT 1024
#define DD 256
#define HH 8
#define BT 8192   // B*T

typedef __attribute__((ext_vector_type(4))) float f32x4;
typedef __attribute__((ext_vector_type(16))) float f32x16;
typedef __attribute__((ext_vector_type(8))) short short8;
typedef __attribute__((ext_vector_type(4))) short short4v;
typedef __attribute__((ext_vector_type(8))) __bf16 bf16x8;

__device__ inline float bf2f(short s) {
  unsigned int u = ((unsigned int)(unsigned short)s) << 16;
  return __builtin_bit_cast(float, u);
}
__device__ inline short f2bf(float f) {
  unsigned int u = __builtin_bit_cast(unsigned int, f);
  unsigned int lsb = (u >> 16) & 1u;
  u += 0x7fffu + lsb;
  return (short)(u >> 16);
}
__device__ inline unsigned int cvtpk(float lo, float hi) {
  unsigned int r;
  asm("v_cvt_pk_bf16_f32 %0, %1, %2" : "=v"(r) : "v"(lo), "v"(hi));
  return r;
}

__device__ inline f32x4 mfma16(short8 a, short8 b, f32x4 c) {
  return __builtin_amdgcn_mfma_f32_16x16x32_bf16(
      __builtin_bit_cast(bf16x8, a), __builtin_bit_cast(bf16x8, b), c, 0, 0, 0);
}
__device__ inline f32x16 mfma32(short8 a, short8 b, f32x16 c) {
  return __builtin_amdgcn_mfma_f32_32x32x16_bf16(
      __builtin_bit_cast(bf16x8, a), __builtin_bit_cast(bf16x8, b), c, 0, 0, 0);
}

__device__ inline void gload_lds16(void* lds, const void* g) {
  __builtin_amdgcn_global_load_lds(
      (const __attribute__((address_space(1))) unsigned int*)g,
      (__attribute__((address_space(3))) unsigned int*)lds, 16, 0, 0);
}

// ---------------- all weights fp32 -> bf16, one kernel ----------------
__global__ __launch_bounds__(256) void cvt_all(
    const float4* __restrict__ s0, short4v* __restrict__ d0, int n0,
    const float4* __restrict__ s1, short4v* __restrict__ d1, int n1,
    const float4* __restrict__ s2, short4v* __restrict__ d2, int n2,
    const float4* __restrict__ s3, short4v* __restrict__ d3, int n3)
{
  int i = blockIdx.x * 256 + threadIdx.x;
  const float4* s; short4v* d;
  if (i < n0) { s = s0 + i; d = d0 + i; }
  else if ((i -= n0) < n1) { s = s1 + i; d = d1 + i; }
  else if ((i -= n1) < n2) { s = s2 + i; d = d2 + i; }
  else if ((i -= n2) < n3) { s = s3 + i; d = d3 + i; }
  else return;
  float4 v = *s;
  short4v o;
  o[0] = f2bf(v.x); o[1] = f2bf(v.y); o[2] = f2bf(v.z); o[3] = f2bf(v.w);
  *d = o;
}

// ---------------- LayerNorm (double LN) — layer-0 entry only ----------------
__global__ __launch_bounds__(256) void ln_kernel(
    const float* __restrict__ Xin,
    const float* __restrict__ g1, const float* __restrict__ b1,
    const float* __restrict__ g2, const float* __restrict__ b2,
    short* __restrict__ out)
{
  const int row = blockIdx.x * 4 + (threadIdx.x >> 6);
  const int lane = threadIdx.x & 63;
  const float4 v = *(const float4*)(Xin + (size_t)row * 256 + lane * 4);
  float y[4] = {v.x, v.y, v.z, v.w};

  float s = y[0] + y[1] + y[2] + y[3];
  #pragma unroll
  for (int m = 32; m >= 1; m >>= 1) s += __shfl_xor(s, m, 64);
  float mean = s * (1.0f / 256.0f);
  float sq = 0.f;
  #pragma unroll
  for (int i = 0; i < 4; ++i) { y[i] -= mean; sq += y[i] * y[i]; }
  #pragma unroll
  for (int m = 32; m >= 1; m >>= 1) sq += __shfl_xor(sq, m, 64);
  float rs = rsqrtf(sq * (1.0f / 256.0f) + 1e-6f);
  #pragma unroll
  for (int i = 0; i < 4; ++i) y[i] = y[i] * rs * g1[lane * 4 + i] + b1[lane * 4 + i];

  float s2 = y[0] + y[1] + y[2] + y[3];
  #pragma unroll
  for (int m = 32; m >= 1; m >>= 1) s2 += __shfl_xor(s2, m, 64);
  float m2 = s2 * (1.0f / 256.0f);
  float sq2 = 0.f;
  #pragma unroll
  for (int i = 0; i < 4; ++i) { y[i] -= m2; sq2 += y[i] * y[i]; }
  #pragma unroll
  for (int m = 32; m >= 1; m >>= 1) sq2 += __shfl_xor(sq2, m, 64);
  float rs2 = rsqrtf(sq2 * (1.0f / 256.0f) + 1e-6f);
  #pragma unroll
  for (int i = 0; i < 4; ++i) y[i] = y[i] * rs2 * g2[lane * 4 + i] + b2[lane * 4 + i];

  #pragma unroll
  for (int i = 0; i < 4; ++i) out[(size_t)row * 256 + lane * 4 + i] = f2bf(y[i]);
}

// ------- GEMM: C[M,N] = A[M,K] @ Bw[N,K]^T, BK=64, 2-phase dbuf staging -------
// EPI 2: Out_bf = bf16(gelu_tanh(acc + bias))                            (FFN1)
// EPI 4: packed qkv: Qp/Kp[(bh)*1024+t][32] (l2normed, Q*C2), vT[bh][d][t] (QKV)
template<int BN, int EPI>
__global__ __launch_bounds__(256) void gemm_bt(
    const short* __restrict__ A, const short* __restrict__ Bw,
    const float* __restrict__ bias,
    short* __restrict__ O0, short* __restrict__ O1, short* __restrict__ O2,
    int M, int N, int K)
{
  constexpr int MI = (BN == 128) ? 4 : 2;
  __shared__ __align__(16) short A_s[2][128 * 64];
  __shared__ __align__(16) short B_s[2][BN * 64];
  const int tid = threadIdx.x;
  const int lane = tid & 63;
  const int w = tid >> 6;
  const int lo4 = lane & 15, hi2 = lane >> 4;
  int wm, wn0;
  if (BN == 128) { wm = (w >> 1) * 64; wn0 = (w & 1) * 64; }
  else           { wm = w * 32;        wn0 = 0; }
  const int bid = blockIdx.x + blockIdx.y * gridDim.x;
  const int nwg = gridDim.x * gridDim.y;
  const int wg = (bid & 7) * (nwg >> 3) + (bid >> 3);
  const int tM = (wg / gridDim.x) * 128, tN = (wg % gridDim.x) * BN;

  f32x4 acc[MI][4];
  #pragma unroll
  for (int i = 0; i < MI; ++i)
    #pragma unroll
    for (int j = 0; j < 4; ++j) acc[i][j] = (f32x4){0.f, 0.f, 0.f, 0.f};

  auto stage = [&](int buf, int k0) {
    #pragma unroll
    for (int ri = 0; ri < 4; ++ri) {
      int o = ri * 2048 + tid * 8;
      int row = o >> 6;
      int col = (o & 63) ^ ((row & 7) << 3);
      gload_lds16(&A_s[buf][ri * 2048 + w * 512], A + (size_t)(tM + row) * K + k0 + col);
    }
    #pragma unroll
    for (int ri = 0; ri < BN / 32; ++ri) {
      int o = ri * 2048 + tid * 8;
      int row = o >> 6;
      int col = (o & 63) ^ ((row & 7) << 3);
      gload_lds16(&B_s[buf][ri * 2048 + w * 512], Bw + (size_t)(tN + row) * K + k0 + col);
    }
  };

  const int nt = K >> 6;
  stage(0, 0);
  __syncthreads();
  for (int t = 0; t < nt; ++t) {
    const int cur = t & 1;
    if (t + 1 < nt) stage(cur ^ 1, (t + 1) << 6);
    #pragma unroll
    for (int kc = 0; kc < 2; ++kc) {
      short8 af[MI], bfr[4];
      #pragma unroll
      for (int i = 0; i < MI; ++i) {
        int row = wm + i * 16 + lo4;
        af[i] = *(const short8*)&A_s[cur][row * 64 + ((kc * 32 + hi2 * 8) ^ ((row & 7) << 3))];
      }
      #pragma unroll
      for (int j = 0; j < 4; ++j) {
        int row = wn0 + j * 16 + lo4;
        bfr[j] = *(const short8*)&B_s[cur][row * 64 + ((kc * 32 + hi2 * 8) ^ ((row & 7) << 3))];
      }
      #pragma unroll
      for (int i = 0; i < MI; ++i)
        #pragma unroll
        for (int j = 0; j < 4; ++j)
          acc[i][j] = mfma16(af[i], bfr[j], acc[i][j]);
    }
    __syncthreads();
  }

  if (EPI == 4) {
    #pragma unroll
    for (int i = 0; i < MI; ++i)
      #pragma unroll
      for (int j = 0; j < 4; ++j)
        #pragma unroll
        for (int r = 0; r < 4; ++r)
          acc[i][j][r] += bias[tN + wn0 + j * 16 + lo4];
    if (tN >= 512) {
      // V: direct transposed write vT[bh][d][t], short4 over r (4 consecutive t)
      #pragma unroll
      for (int i = 0; i < MI; ++i) {
        #pragma unroll
        for (int j = 0; j < 4; ++j) {
          short4v o;
          #pragma unroll
          for (int r = 0; r < 4; ++r) o[r] = f2bf(acc[i][j][r]);
          int row0 = tM + wm + i * 16 + hi2 * 4;
          int colr = (tN + wn0 + j * 16 + lo4) - 512;
          int h = colr >> 5, d = colr & 31;
          int b = row0 >> 10, t0 = row0 & 1023;
          *(short4v*)(O2 + (((size_t)(b * 8 + h) * 32 + d) << 10) + t0) = o;
        }
      }
      return;
    }
    {  // Q or K: per-head l2norm (j-pairs {0,1},{2,3})
      const float C2 = 0.25503489702966368f;   // (1/sqrt(32)) * log2(e)
      const float sc = (tN < 256) ? C2 : 1.0f;
      #pragma unroll
      for (int i = 0; i < MI; ++i) {
        #pragma unroll
        for (int r = 0; r < 4; ++r) {
          float s01 = acc[i][0][r] * acc[i][0][r] + acc[i][1][r] * acc[i][1][r];
          float s23 = acc[i][2][r] * acc[i][2][r] + acc[i][3][r] * acc[i][3][r];
          #pragma unroll
          for (int m = 1; m <= 8; m <<= 1) {
            s01 += __shfl_xor(s01, m, 64);
            s23 += __shfl_xor(s23, m, 64);
          }
          float n01 = sc / fmaxf(sqrtf(s01), 1e-8f);
          float n23 = sc / fmaxf(sqrtf(s23), 1e-8f);
          acc[i][0][r] *= n01; acc[i][1][r] *= n01;
          acc[i][2][r] *= n23; acc[i][3][r] *= n23;
        }
      }
    }
    short* dst = (tN < 256) ? O0 : O1;
    #pragma unroll
    for (int i = 0; i < MI; ++i)
      #pragma unroll
      for (int j = 0; j < 4; ++j)
        #pragma unroll
        for (int r = 0; r < 4; ++r) {
          int row = tM + wm + i * 16 + hi2 * 4 + r;
          int colr = (tN + wn0 + j * 16 + lo4) & 255;
          int h = colr >> 5, d = colr & 31;
          size_t idx = (((size_t)((row >> 10) * 8 + h) << 10) | (size_t)(row & 1023)) * 32 + d;
          dst[idx] = f2bf(acc[i][j][r]);
        }
    return;
  }

  #pragma unroll
  for (int i = 0; i < MI; ++i) {
    #pragma unroll
    for (int j = 0; j < 4; ++j) {
      #pragma unroll
      for (int r = 0; r < 4; ++r) {
        int row = tM + wm + i * 16 + hi2 * 4 + r;
        int col = tN + wn0 + j * 16 + lo4;
        float v = acc[i][j][r] + bias[col];
        size_t idx = (size_t)row * N + col;
        if (EPI == 2) {
          // gelu tanh-form: v * t/(t+1), t = exp2(2*y*log2e)
          float t1 = v * v;
          float arg = fminf(v * (1.0f + 0.044715f * t1) * 2.3022077f, 80.0f);
          float ex;
          asm("v_exp_f32 %0, %1" : "=v"(ex) : "v"(arg));
          float gl = v * ex * __builtin_amdgcn_rcpf(ex + 1.0f);
          O0[idx] = f2bf(gl);
        } else {
          O0[idx] = f2bf(v);
        }
      }
    }
  }
}

// ---- gemm_ln: BM=32 full-row; 512 threads / 8 waves (wave = 32-col span) ----
// MODE 0 (Wo):   X = Xin + ts*0.5*(acc+bias);        h = LN(X; gA,bA)
// MODE 1 (FFN2): X = clip(X + ts*(acc+bias), ±100);  h = LN(LN(X;gA,bA); gB,bB) if doLN
template<int MODE>
__global__ __launch_bounds__(512) void gemm_ln(
    const short* __restrict__ A, const short* __restrict__ Bw,
    const float* __restrict__ bias, const float* Xin, float* X,
    short* __restrict__ Obf, const float* __restrict__ scale_p,
    const float* __restrict__ gA, const float* __restrict__ bA,
    const float* __restrict__ gB, const float* __restrict__ bB,
    int K, int doLN)
{
  __shared__ __align__(16) short A_s[2][32 * 64];
  __shared__ __align__(16) short B_s[2][256 * 64];
  __shared__ float Red[2][32][8][2];
  const int tid = threadIdx.x;
  const int lane = tid & 63;
  const int w = tid >> 6;                // 0..7
  const int lo4 = lane & 15, hi2 = lane >> 4;
  const int tM = blockIdx.x * 32;
  const int wn0 = w * 32;                // wave's 32-col span

  f32x4 acc[2][2];
  #pragma unroll
  for (int i = 0; i < 2; ++i)
    #pragma unroll
    for (int j = 0; j < 2; ++j) acc[i][j] = (f32x4){0.f, 0.f, 0.f, 0.f};

  auto stage = [&](int buf, int k0) {
    if (tid < 256) {
      int o = tid * 8;
      int row = o >> 6;
      int col = (o & 63) ^ ((row & 7) << 3);
      gload_lds16(&A_s[buf][w * 512], A + (size_t)(tM + row) * K + k0 + col);
    }
    #pragma unroll
    for (int ri = 0; ri < 4; ++ri) {
      int o = ri * 4096 + tid * 8;
      int row = o >> 6;
      int col = (o & 63) ^ ((row & 7) << 3);
      gload_lds16(&B_s[buf][ri * 4096 + w * 512], Bw + (size_t)row * K + k0 + col);
    }
  };

  const int nt = K >> 6;
  stage(0, 0);
  __syncthreads();
  for (int t = 0; t < nt; ++t) {
    const int cur = t & 1;
    if (t + 1 < nt) stage(cur ^ 1, (t + 1) << 6);
    #pragma unroll
    for (int kc = 0; kc < 2; ++kc) {
      short8 af[2], bfr[2];
      #pragma unroll
      for (int i = 0; i < 2; ++i) {
        int row = i * 16 + lo4;
        af[i] = *(const short8*)&A_s[cur][row * 64 + ((kc * 32 + hi2 * 8) ^ ((row & 7) << 3))];
      }
      #pragma unroll
      for (int j = 0; j < 2; ++j) {
        int row = wn0 + j * 16 + lo4;
        bfr[j] = *(const short8*)&B_s[cur][row * 64 + ((kc * 32 + hi2 * 8) ^ ((row & 7) << 3))];
      }
      #pragma unroll
      for (int i = 0; i < 2; ++i)
        #pragma unroll
        for (int j = 0; j < 2; ++j)
          acc[i][j] = mfma16(af[i], bfr[j], acc[i][j]);
    }
    __syncthreads();
  }

  const float ts = tanhf(scale_p[0]);
  float xv[2][2][4];
  #pragma unroll
  for (int i = 0; i < 2; ++i)
    #pragma unroll
    for (int j = 0; j < 2; ++j)
      #pragma unroll
      for (int r = 0; r < 4; ++r) {
        int row = i * 16 + hi2 * 4 + r;
        int col = wn0 + j * 16 + lo4;
        float v = acc[i][j][r] + bias[col];
        size_t idx = (size_t)(tM + row) * 256 + col;
        float xn;
        if (MODE == 0) {
          xn = Xin[idx] + ts * 0.5f * v;
        } else {
          xn = X[idx] + ts * v;
          xn = fminf(100.f, fmaxf(-100.f, xn));
        }
        X[idx] = xn;
        xv[i][j][r] = xn;
      }

  if (!doLN) return;

  #pragma unroll
  for (int i = 0; i < 2; ++i)
    #pragma unroll
    for (int r = 0; r < 4; ++r) {
      float s = xv[i][0][r] + xv[i][1][r];
      float q = xv[i][0][r] * xv[i][0][r] + xv[i][1][r] * xv[i][1][r];
      #pragma unroll
      for (int m = 1; m <= 8; m <<= 1) { s += __shfl_xor(s, m, 64); q += __shfl_xor(q, m, 64); }
      if (lo4 == 0) { Red[0][i * 16 + hi2 * 4 + r][w][0] = s; Red[0][i * 16 + hi2 * 4 + r][w][1] = q; }
    }
  __syncthreads();
  #pragma unroll
  for (int i = 0; i < 2; ++i)
    #pragma unroll
    for (int r = 0; r < 4; ++r) {
      int row = i * 16 + hi2 * 4 + r;
      float s = 0.f, q = 0.f;
      #pragma unroll
      for (int ww = 0; ww < 8; ++ww) { s += Red[0][row][ww][0]; q += Red[0][row][ww][1]; }
      float mu = s * (1.0f / 256.0f);
      float var = q * (1.0f / 256.0f) - mu * mu;
      float rs = rsqrtf(var + 1e-6f);
      #pragma unroll
      for (int j = 0; j < 2; ++j) {
        int col = wn0 + j * 16 + lo4;
        xv[i][j][r] = (xv[i][j][r] - mu) * rs * gA[col] + bA[col];
      }
    }

  if (MODE == 1) {
    __syncthreads();
    #pragma unroll
    for (int i = 0; i < 2; ++i)
      #pragma unroll
      for (int r = 0; r < 4; ++r) {
        float s = xv[i][0][r] + xv[i][1][r];
        float q = xv[i][0][r] * xv[i][0][r] + xv[i][1][r] * xv[i][1][r];
        #pragma unroll
        for (int m = 1; m <= 8; m <<= 1) { s += __shfl_xor(s, m, 64); q += __shfl_xor(q, m, 64); }
        if (lo4 == 0) { Red[1][i * 16 + hi2 * 4 + r][w][0] = s; Red[1][i * 16 + hi2 * 4 + r][w][1] = q; }
      }
    __syncthreads();
    #pragma unroll
    for (int i = 0; i < 2; ++i)
      #pragma unroll
      for (int r = 0; r < 4; ++r) {
        int row = i * 16 + hi2 * 4 + r;
        float s = 0.f, q = 0.f;
        #pragma unroll
        for (int ww = 0; ww < 8; ++ww) { s += Red[1][row][ww][0]; q += Red[1][row][ww][1]; }
        float mu = s * (1.0f / 256.0f);
        float var = q * (1.0f / 256.0f) - mu * mu;
        float rs = rsqrtf(var + 1e-6f);
        #pragma unroll
        for (int j = 0; j < 2; ++j) {
          int col = wn0 + j * 16 + lo4;
          xv[i][j][r] = (xv[i][j][r] - mu) * rs * gB[col] + bB[col];
        }
      }
  }

  #pragma unroll
  for (int i = 0; i < 2; ++i)
    #pragma unroll
    for (int j = 0; j < 2; ++j)
      #pragma unroll
      for (int r = 0; r < 4; ++r) {
        int row = i * 16 + hi2 * 4 + r;
        int col = wn0 + j * 16 + lo4;
        Obf[(size_t)(tM + row) * 256 + col] = f2bf(xv[i][j][r]);
      }
}

// ------- fused causal attention: packed Qp/Kp/vT, 2-way KV split per q-tile -----
__device__ __forceinline__ void pv_acc(const unsigned int* PKO, int half_,
                                       short8 vb, int hi1, f32x16& acc) {
  unsigned int keep0 = hi1 ? PKO[4 * half_ + 2] : PKO[4 * half_ + 0];
  unsigned int keep1 = hi1 ? PKO[4 * half_ + 3] : PKO[4 * half_ + 1];
  unsigned int send0 = hi1 ? PKO[4 * half_ + 0] : PKO[4 * half_ + 2];
  unsigned int send1 = hi1 ? PKO[4 * half_ + 1] : PKO[4 * half_ + 3];
  unsigned int r0 = (unsigned int)__shfl_xor((int)send0, 32, 64);
  unsigned int r1 = (unsigned int)__shfl_xor((int)send1, 32, 64);
  union { unsigned int u[4]; short8 s; } fa;
  fa.u[0] = hi1 ? r0 : keep0;
  fa.u[1] = hi1 ? r1 : keep1;
  fa.u[2] = hi1 ? keep0 : r0;
  fa.u[3] = hi1 ? keep1 : r1;
  acc = mfma32(fa.s, vb, acc);
}

template<bool KG1, bool M0, bool M1>
__device__ __forceinline__ void attn_tile(
    int t, const short* __restrict__ Kbase, const short* __restrict__ VTl,
    const short8* qb, unsigned int pm0, unsigned int pm1, int lo5, int hi1,
    f32x16& oaccA, f32x16& oaccB, float& rsum)
{
  const short* kp0 = Kbase + (size_t)(t * 64 + lo5) * 32;
  short8 k00 = *(const short8*)(kp0 + hi1 * 8);
  short8 k01 = *(const short8*)(kp0 + 16 + hi1 * 8);
  short8 k10, k11;
  if (KG1) {
    const short* kp1 = Kbase + (size_t)(t * 64 + 32 + lo5) * 32;
    k10 = *(const short8*)(kp1 + hi1 * 8);
    k11 = *(const short8*)(kp1 + 16 + hi1 * 8);
  }
  const short* vp = VTl + t * 64 + hi1 * 8;
  short8 vb0 = *(const short8*)(vp);
  short8 vb1 = *(const short8*)(vp + 16);
  short8 vb2, vb3;
  if (KG1) {
    vb2 = *(const short8*)(vp + 32);
    vb3 = *(const short8*)(vp + 48);
  }
  unsigned int pk0[8], pk1[8];
  {
    f32x16 z = (f32x16)0.0f;
    z = mfma32(k00, qb[0], z);
    z = mfma32(k01, qb[1], z);
    float pr[16];
    #pragma unroll
    for (int r = 0; r < 16; ++r) {
      float sv = __builtin_amdgcn_fmed3f(z[r], -14.4269504f, 14.4269504f);
      float pe;
      asm("v_exp_f32 %0, %1" : "=v"(pe) : "v"(sv));
      const int keyrel = (r & 3) + 8 * (r >> 2) + 4 * hi1;
      if (M0) pe = (keyrel > lo5) ? 0.f : pe;
      if (pm0) pe = ((pm0 >> keyrel) & 1u) ? 0.f : pe;
      pr[r] = pe;
      rsum += pe;
    }
    #pragma unroll
    for (int i = 0; i < 8; ++i) pk0[i] = cvtpk(pr[2 * i], pr[2 * i + 1]);
  }
  if (KG1) {
    f32x16 z = (f32x16)0.0f;
    z = mfma32(k10, qb[0], z);
    z = mfma32(k11, qb[1], z);
    float pr[16];
    #pragma unroll
    for (int r = 0; r < 16; ++r) {
      float sv = __builtin_amdgcn_fmed3f(z[r], -14.4269504f, 14.4269504f);
      float pe;
      asm("v_exp_f32 %0, %1" : "=v"(pe) : "v"(sv));
      const int keyrel = (r & 3) + 8 * (r >> 2) + 4 * hi1;
      if (M1) pe = (keyrel > lo5) ? 0.f : pe;
      if (pm1) pe = ((pm1 >> keyrel) & 1u) ? 0.f : pe;
      pr[r] = pe;
      rsum += pe;
    }
    #pragma unroll
    for (int i = 0; i < 8; ++i) pk1[i] = cvtpk(pr[2 * i], pr[2 * i + 1]);
  }
  pv_acc(pk0, 0, vb0, hi1, oaccA);
  pv_acc(pk0, 1, vb1, hi1, oaccB);
  if (KG1) {
    pv_acc(pk1, 0, vb2, hi1, oaccA);
    pv_acc(pk1, 1, vb3, hi1, oaccB);
  }
}

__global__ __launch_bounds__(256, 2) void attn_kernel(
    const short* __restrict__ Qp, const short* __restrict__ Kp,
    const short* __restrict__ vT, const unsigned char* __restrict__ pad,
    short* __restrict__ ao)
{
  __shared__ float Red[2][17][64];
  const int tid = threadIdx.x, lane = tid & 63, w = tid >> 6;
  const int lo5 = lane & 31, hi1 = lane >> 5;
  const int bid = blockIdx.x;            // 1024
  const int b = bid & 7;                 // XCD-local batch
  const int h = (bid >> 3) & 7;
  const int bj = bid >> 6;               // 0..15
  const int p = w >> 1;                  // pair id
  const int half = w & 1;                // t-parity this wave owns
  const int j = p ? (31 - bj) : bj;      // q-tile 0..31
  const size_t rowbase = (size_t)b * TT;
  const int bh = b * 8 + h;
  const int qrow = j * 32 + lo5;
  const int ntile = (j >> 1) + 1;

  const short* Kbase = Kp + ((size_t)bh << 10) * 32;
  const short* VTl = vT + ((size_t)bh * 32 + lo5) * 1024;

  const ulonglong2 pv = *(const ulonglong2*)(pad + rowbase + lane * 16);
  const unsigned long long anyp = __ballot((pv.x | pv.y) != 0ull);

  short8 qb[2];
  #pragma unroll
  for (int c2 = 0; c2 < 2; ++c2)
    qb[c2] = *(const short8*)(Qp + (((size_t)bh << 10) + qrow) * 32 + c2 * 16 + hi1 * 8);

  f32x16 oaccA = (f32x16)0.0f;
  f32x16 oaccB = (f32x16)0.0f;
  float rsum = 0.f;

  for (int t = half; t < ntile; t += 2) {
    unsigned long long pm = 0;
    if ((anyp >> (4 * t)) & 0xFull)
      pm = __ballot(pad[rowbase + t * 64 + lane] != 0);
    unsigned int pm0 = (unsigned int)pm, pm1 = (unsigned int)(pm >> 32);
    if (t + 1 < ntile)
      attn_tile<true, false, false>(t, Kbase, VTl, qb, pm0, pm1, lo5, hi1, oaccA, oaccB, rsum);
    else if (j & 1)
      attn_tile<true, false, true>(t, Kbase, VTl, qb, pm0, pm1, lo5, hi1, oaccA, oaccB, rsum);
    else
      attn_tile<false, true, false>(t, Kbase, VTl, qb, pm0, pm1, lo5, hi1, oaccA, oaccB, rsum);
  }

  if (half) {
    #pragma unroll
    for (int r = 0; r < 16; ++r) Red[p][r][lane] = oaccA[r] + oaccB[r];
    Red[p][16][lane] = rsum;
  }
  __syncthreads();
  if (!half) {
    #pragma unroll
    for (int r = 0; r < 16; ++r) oaccA[r] += oaccB[r] + Red[p][r][lane];
    rsum += Red[p][16][lane];
    rsum += __shfl_xor(rsum, 32, 64);
    float rinv = 1.0f / fmaxf(rsum, 1e-30f);
    #pragma unroll
    for (int r = 0; r < 16; ++r) {
      int ql = (r & 3) + 8 * (r >> 2) + 4 * hi1;
      float riv = __shfl(rinv, ql, 64);
      int qg = j * 32 + ql;
      ao[(rowbase + qg) * 256 + h * 32 + lo5] = f2bf(oaccA[r] * riv);
    }
  }
}

extern "C" void kernel_launch(void* const* d_in, const int* in_sizes, int n_in,
                              void* d_out, int out_size, void* d_ws, size_t ws_size,
                              hipStream_t stream) {
  const float* x_in  = (const float*)d_in[0];
  const unsigned char* pad = (const unsigned char*)d_in[1];
  const float* ln1_g = (const float*)d_in[2];
  const float* ln1_b = (const float*)d_in[3];
  const float* qn_g  = (const float*)d_in[4];
  const float* qn_b  = (const float*)d_in[5];
  const float* Wqkv  = (const float*)d_in[6];
  const float* bqkv  = (const float*)d_in[7];
  const float* Wo    = (const float*)d_in[8];
  const float* bo    = (const float*)d_in[9];
  const float* ln2_g = (const float*)d_in[10];
  const float* ln2_b = (const float*)d_in[11];
  const float* W1    = (const float*)d_in[12];
  const float* b1    = (const float*)d_in[13];
  const float* W2    = (const float*)d_in[14];
  const float* b2    = (const float*)d_in[15];
  const float* alpha = (const float*)d_in[16];
  const float* beta  = (const float*)d_in[17];

  char* ws = (char*)d_ws;
  size_t off = 0;
  short* wqkv_bf = (short*)(ws + off); off += (size_t)4 * 768 * 256 * 2;
  short* wo_bf   = (short*)(ws + off); off += (size_t)4 * 256 * 256 * 2;
  short* w1_bf   = (short*)(ws + off); off += (size_t)4 * 1024 * 256 * 2;
  short* w2_bf   = (short*)(ws + off); off += (size_t)4 * 256 * 1024 * 2;
  short* h_bf    = (short*)(ws + off); off += (size_t)BT * 256 * 2;
  short* Qp_bf   = (short*)(ws + off); off += (size_t)BT * 256 * 2;
  short* Kp_bf   = (short*)(ws + off); off += (size_t)BT * 256 * 2;
  short* vT_bf   = (short*)(ws + off); off += (size_t)BT * 256 * 2;
  short* ao_bf   = (short*)(ws + off); off += (size_t)BT * 256 * 2;
  short* g_bf    = (short*)(ws + off); off += (size_t)BT * 1024 * 2;

  float* X = (float*)d_out;

  cvt_all<<<3072, 256, 0, stream>>>(
      (const float4*)Wqkv, (short4v*)wqkv_bf, 4 * 768 * 256 / 4,
      (const float4*)Wo,   (short4v*)wo_bf,   4 * 256 * 256 / 4,
      (const float4*)W1,   (short4v*)w1_bf,   4 * 1024 * 256 / 4,
      (const float4*)W2,   (short4v*)w2_bf,   4 * 256 * 1024 / 4);

  // layer-0 entry LN (double) reads x_in directly
  ln_kernel<<<2048, 256, 0, stream>>>(x_in, ln1_g, ln1_b, qn_g, qn_b, h_bf);

  for (int l = 0; l < 4; ++l) {
    gemm_bt<64, 4><<<dim3(12, 64), 256, 0, stream>>>(h_bf, wqkv_bf + (size_t)l * 768 * 256,
                                                     bqkv + l * 768, Qp_bf, Kp_bf, vT_bf,
                                                     8192, 768, 256);
    attn_kernel<<<1024, 256, 0, stream>>>(Qp_bf, Kp_bf, vT_bf, pad, ao_bf);
    gemm_ln<0><<<256, 512, 0, stream>>>(ao_bf, wo_bf + (size_t)l * 256 * 256,
                                        bo + l * 256, (l == 0) ? x_in : (const float*)X, X,
                                        h_bf, alpha + l,
                                        ln2_g + l * 256, ln2_b + l * 256,
                                        nullptr, nullptr, 256, 1);
    gemm_bt<128, 2><<<dim3(8, 64), 256, 0, stream>>>(h_bf, w1_bf + (size_t)l * 1024 * 256,
                                                     b1 + l * 1024, g_bf, nullptr, nullptr,
                                                     8192, 1024, 256);
    const int nl = (l < 3) ? (l + 1) : 0;  // dummy params when doLN=0
    gemm_ln<1><<<256, 512, 0, stream>>>(g_bf, w2_bf + (size_t)l * 256 * 1024,
                                        b2 + l * 256, X, X, h_bf, beta + l,
                                        ln1_g + nl * 256, ln1_b + nl * 256,
                                        qn_g + nl * 256, qn_b + nl * 256,
                                        1024, (l < 3) ? 1 : 0);
  }
}